// Round 5
// baseline (75.633 us; speedup 1.0000x reference)
//
#include <hip/hip_runtime.h>

constexpr int kN = 4, kC = 19, kH = 512, kW = 512;
constexpr int kHW = kH * kW;
constexpr int kS = 2048;      // NUM_SUPERPIXEL
constexpr int kSsm = 8192;    // NUM_SMALL
constexpr float kEps = 1e-8f;

constexpr int kNSC = kN * kS * kC;                 // combine domain (155,648)
constexpr int kCombineBlocks = 64;                 // grid-stride; ticket-friendly

// ---- workspace layout (bytes) ----
// Zeroed region first (amax, sumpool, counts, needmask, ticket), then
// fully-overwritten buffers (tmask, partials).
constexpr size_t OFF_AMAX = 0;                                   // u64[N*S*C] (value_bits<<32)|~pix
constexpr size_t SZ_AMAX  = (size_t)kN * kS * kC * 8;
constexpr size_t OFF_SUM  = OFF_AMAX + SZ_AMAX;                  // f32[N*Ssm*C] nll sumpool
constexpr size_t SZ_SUM   = (size_t)kN * kSsm * kC * 4;
constexpr size_t OFF_CNT  = OFF_SUM + SZ_SUM;                    // i32[N*Ssm]
constexpr size_t SZ_CNT   = (size_t)kN * kSsm * 4;
constexpr size_t OFF_NM   = OFF_CNT + SZ_CNT;                    // u32[N*Ssm] needed (small,ch) bits
constexpr size_t SZ_NM    = (size_t)kN * kSsm * 4;
constexpr size_t OFF_TK   = OFF_NM + SZ_NM;                      // u32 ticket (padded to 16B)
constexpr size_t SZ_TK    = 16;
constexpr size_t ZERO_BYTES = OFF_TK + SZ_TK;                    // everything above is zeroed
constexpr size_t ZERO_CHUNKS = ZERO_BYTES / 16;                  // 16B chunks (sizes are multiples)
constexpr size_t OFF_TM   = ZERO_BYTES;                          // u32[N*S] target channel bitmask
constexpr size_t SZ_TM    = (size_t)kN * kS * 4;
constexpr size_t OFF_PL   = OFF_TM + SZ_TM;                      // f32[kCombineBlocks]
constexpr size_t SZ_PL    = (size_t)kCombineBlocks * 4;
constexpr size_t OFF_PN   = OFF_PL + SZ_PL;                      // i32[kCombineBlocks]
constexpr size_t SZ_PN    = (size_t)kCombineBlocks * 4;
constexpr size_t WS_TOTAL = OFF_PN + SZ_PN;

// Fused: zero the accumulator region + build tmask (R3 lesson: runtime
// memset is cheap in-graph, but fusing drops a node anyway).
__global__ void init_kernel(const float* __restrict__ targets,
                            unsigned* __restrict__ tmask,
                            ulong2* __restrict__ ws) {
    size_t gid = (size_t)blockIdx.x * blockDim.x + threadIdx.x;
    if (gid < ZERO_CHUNKS) ws[gid] = ulong2{0ULL, 0ULL};
    if (gid < (size_t)kN * kS) {
        const float* t = targets + gid * (kC + 1);
        unsigned m = 0;
#pragma unroll
        for (int c = 0; c < kC; ++c)
            if (t[c] > 0.f) m |= (1u << c);
        tmask[gid] = m;
    }
}

// Weak branch, 2 pixels/thread: softmax over C, per-(segment,channel)
// lexicographic argmax via u64 atomicMax of (float_bits(v)<<32)|~pixel,
// only for target channels. Atomic count is the live-incidence minimum.
__global__ void weak_argmax_kernel(const float* __restrict__ logits,
                                   const unsigned char* __restrict__ mask,
                                   const int* __restrict__ seg,
                                   const unsigned* __restrict__ tmask,
                                   unsigned long long* __restrict__ amax) {
    int t = blockIdx.x * blockDim.x + threadIdx.x;
    if (t >= kN * kHW / 2) return;
    int n = t / (kHW / 2);
    int p = (t - n * (kHW / 2)) * 2;
    int pixbase = n * kHW + p;

    uchar2 mk = *(const uchar2*)&mask[pixbase];
    int2 sg = *(const int2*)&seg[pixbase];
    unsigned tm0 = mk.x ? tmask[n * kS + sg.x] : 0u;
    unsigned tm1 = mk.y ? tmask[n * kS + sg.y] : 0u;
    if (!(tm0 | tm1)) return;

    const float* base = logits + (size_t)n * kC * kHW + p;
    float2 x[kC];
    float m0 = -1e30f, m1 = -1e30f;
#pragma unroll
    for (int c = 0; c < kC; ++c) {
        x[c] = *(const float2*)&base[(size_t)c * kHW];
        m0 = fmaxf(m0, x[c].x);
        m1 = fmaxf(m1, x[c].y);
    }
    float s0 = 0.f, s1 = 0.f;
#pragma unroll
    for (int c = 0; c < kC; ++c) {
        x[c].x = expf(x[c].x - m0);
        x[c].y = expf(x[c].y - m1);
        s0 += x[c].x;
        s1 += x[c].y;
    }
    float inv0 = 1.f / s0, inv1 = 1.f / s1;

    unsigned long long lo0 = (unsigned)~(unsigned)p;
    unsigned long long lo1 = (unsigned)~(unsigned)(p + 1);
    unsigned long long* dst0 = amax + ((size_t)n * kS + sg.x) * kC;
    unsigned long long* dst1 = amax + ((size_t)n * kS + sg.y) * kC;
#pragma unroll
    for (int c = 0; c < kC; ++c) {
        if ((tm0 >> c) & 1u) {
            unsigned long long key =
                ((unsigned long long)__float_as_uint(x[c].x * inv0) << 32) | lo0;
            atomicMax(&dst0[c], key);
        }
        if ((tm1 >> c) & 1u) {
            unsigned long long key =
                ((unsigned long long)__float_as_uint(x[c].y * inv1) << 32) | lo1;
            atomicMax(&dst1[c], key);
        }
    }
}

// Mark which (small, channel) pairs the combine stage will read.
__global__ void need_mark_kernel(const unsigned long long* __restrict__ amax,
                                 const unsigned* __restrict__ tmask,
                                 const int* __restrict__ small_w,
                                 unsigned* __restrict__ needmask) {
    int gid = blockIdx.x * blockDim.x + threadIdx.x;
    if (gid >= kNSC) return;
    int n = gid / (kS * kC);
    int rem = gid - n * (kS * kC);
    int s = rem / kC;
    int c = rem - s * kC;
    if (!((tmask[n * kS + s] >> c) & 1u)) return;
    unsigned long long packed = amax[gid];
    if (packed == 0ULL) return;  // empty segment
    unsigned pix = ~(unsigned)(packed & 0xFFFFFFFFULL);
    int sel = small_w[(size_t)n * kHW + pix];
    atomicOr(&needmask[n * kSsm + sel], 1u << c);
}

// Strong branch, 2 pixels/thread: only pixels whose small-superpixel is
// needed; only needed channels get the nll atomicAdd.
__global__ void strong_sumpool_kernel(const float* __restrict__ logits,
                                      const unsigned char* __restrict__ mask,
                                      const int* __restrict__ seg,
                                      const unsigned* __restrict__ needmask,
                                      float* __restrict__ sumpool,
                                      int* __restrict__ counts) {
    int t = blockIdx.x * blockDim.x + threadIdx.x;
    if (t >= kN * kHW / 2) return;
    int n = t / (kHW / 2);
    int p = (t - n * (kHW / 2)) * 2;
    int pixbase = n * kHW + p;

    uchar2 mk = *(const uchar2*)&mask[pixbase];
    int2 sg = *(const int2*)&seg[pixbase];
    unsigned nm0 = mk.x ? needmask[n * kSsm + sg.x] : 0u;
    unsigned nm1 = mk.y ? needmask[n * kSsm + sg.y] : 0u;
    if (!(nm0 | nm1)) return;

    const float* base = logits + (size_t)n * kC * kHW + p;
    float2 x[kC];
    float m0 = -1e30f, m1 = -1e30f;
#pragma unroll
    for (int c = 0; c < kC; ++c) {
        x[c] = *(const float2*)&base[(size_t)c * kHW];
        m0 = fmaxf(m0, x[c].x);
        m1 = fmaxf(m1, x[c].y);
    }
    float s0 = 0.f, s1 = 0.f;
#pragma unroll
    for (int c = 0; c < kC; ++c) {
        x[c].x = expf(x[c].x - m0);
        x[c].y = expf(x[c].y - m1);
        s0 += x[c].x;
        s1 += x[c].y;
    }
    float inv0 = 1.f / s0, inv1 = 1.f / s1;

    float* dst0 = sumpool + ((size_t)n * kSsm + sg.x) * kC;
    float* dst1 = sumpool + ((size_t)n * kSsm + sg.y) * kC;
#pragma unroll
    for (int c = 0; c < kC; ++c) {
        if ((nm0 >> c) & 1u)
            atomicAdd(&dst0[c], -logf(x[c].x * inv0 + kEps));
        if ((nm1 >> c) & 1u)
            atomicAdd(&dst1[c], -logf(x[c].y * inv1 + kEps));
    }
    if (nm0) atomicAdd(&counts[n * kSsm + sg.x], 1);
    if (nm1) atomicAdd(&counts[n * kSsm + sg.y], 1);
}

// Combine + finalize fused: grid-stride over (n,s,c); per-block partials;
// last block (threadfence+ticket) reduces the 64 partials and divides.
// (R1 lesson: never funnel thousands of same-address atomics.)
__global__ void combine_kernel(const unsigned long long* __restrict__ amax,
                               const unsigned* __restrict__ tmask,
                               const int* __restrict__ small_w,
                               const float* __restrict__ sumpool,
                               const int* __restrict__ counts,
                               float* __restrict__ ploss,
                               int* __restrict__ pnv,
                               unsigned* __restrict__ ticket,
                               float* __restrict__ out) {
    __shared__ float sLoss[4];
    __shared__ int sNv[4];
    __shared__ bool amLast;
    float lv = 0.f;
    int nvv = 0;
    for (int gid = blockIdx.x * blockDim.x + threadIdx.x; gid < kNSC;
         gid += kCombineBlocks * 256) {
        int n = gid / (kS * kC);
        int rem = gid - n * (kS * kC);
        int s = rem / kC;
        int c = rem - s * kC;
        if (!((tmask[n * kS + s] >> c) & 1u)) continue;
        unsigned long long packed = amax[gid];
        if (packed == 0ULL) continue;
        unsigned pix = ~(unsigned)(packed & 0xFFFFFFFFULL);
        int sel = small_w[(size_t)n * kHW + pix];
        lv += sumpool[((size_t)n * kSsm + sel) * kC + c];
        nvv += counts[n * kSsm + sel];
    }
#pragma unroll
    for (int off = 32; off > 0; off >>= 1) {
        lv += __shfl_down(lv, off);
        nvv += __shfl_down(nvv, off);
    }
    int wave = threadIdx.x >> 6;
    if ((threadIdx.x & 63) == 0) {
        sLoss[wave] = lv;
        sNv[wave] = nvv;
    }
    __syncthreads();
    if (threadIdx.x == 0) {
        ploss[blockIdx.x] = sLoss[0] + sLoss[1] + sLoss[2] + sLoss[3];
        pnv[blockIdx.x]   = sNv[0] + sNv[1] + sNv[2] + sNv[3];
        __threadfence();
        unsigned prev = atomicAdd(ticket, 1u);
        amLast = (prev == kCombineBlocks - 1);
    }
    __syncthreads();
    if (amLast) {
        __threadfence();
        float tl = 0.f;
        int tn = 0;
        if (threadIdx.x < kCombineBlocks) {
            tl = ((volatile float*)ploss)[threadIdx.x];
            tn = ((volatile int*)pnv)[threadIdx.x];
        }
        if (threadIdx.x < 64) {
#pragma unroll
            for (int off = 32; off > 0; off >>= 1) {
                tl += __shfl_down(tl, off);
                tn += __shfl_down(tn, off);
            }
            if (threadIdx.x == 0) out[0] = tl / (float)(1 + tn);
        }
    }
}

extern "C" void kernel_launch(void* const* d_in, const int* in_sizes, int n_in,
                              void* d_out, int out_size, void* d_ws, size_t ws_size,
                              hipStream_t stream) {
    const float* inputs            = (const float*)d_in[0];
    const float* inputs_weak       = (const float*)d_in[1];
    const float* targets           = (const float*)d_in[2];
    const unsigned char* spmasks      = (const unsigned char*)d_in[3];
    const unsigned char* spmasks_weak = (const unsigned char*)d_in[4];
    // d_in[5] superpixels: unused by the reference
    const int* superpixels_weak    = (const int*)d_in[6];
    const int* superpixel_smalls   = (const int*)d_in[7];
    const int* spx_smalls_weak     = (const int*)d_in[8];
    float* out = (float*)d_out;

    unsigned long long* amax = (unsigned long long*)((char*)d_ws + OFF_AMAX);
    float* sumpool           = (float*)((char*)d_ws + OFF_SUM);
    int* counts              = (int*)((char*)d_ws + OFF_CNT);
    unsigned* needmask       = (unsigned*)((char*)d_ws + OFF_NM);
    unsigned* ticket         = (unsigned*)((char*)d_ws + OFF_TK);
    unsigned* tmask          = (unsigned*)((char*)d_ws + OFF_TM);
    float* ploss             = (float*)((char*)d_ws + OFF_PL);
    int* pnv                 = (int*)((char*)d_ws + OFF_PN);

    int initThreads = (int)ZERO_CHUNKS;  // 249,857 > kN*kS
    init_kernel<<<(initThreads + 255) / 256, 256, 0, stream>>>(targets, tmask,
                                                               (ulong2*)d_ws);
    int pairTotal = kN * kHW / 2;
    int pairBlocks = (pairTotal + 255) / 256;
    weak_argmax_kernel<<<pairBlocks, 256, 0, stream>>>(inputs_weak, spmasks_weak,
                                                       superpixels_weak, tmask, amax);
    need_mark_kernel<<<(kNSC + 255) / 256, 256, 0, stream>>>(amax, tmask,
                                                             spx_smalls_weak, needmask);
    strong_sumpool_kernel<<<pairBlocks, 256, 0, stream>>>(inputs, spmasks,
                                                          superpixel_smalls,
                                                          needmask, sumpool, counts);
    combine_kernel<<<kCombineBlocks, 256, 0, stream>>>(amax, tmask, spx_smalls_weak,
                                                       sumpool, counts, ploss, pnv,
                                                       ticket, out);
}

// Round 6
// 64.864 us; speedup vs baseline: 1.1660x; 1.1660x over previous
//
#include <hip/hip_runtime.h>

constexpr int kN = 4, kC = 19, kH = 512, kW = 512;
constexpr int kHW = kH * kW;
constexpr int kS = 2048;      // NUM_SUPERPIXEL
constexpr int kSsm = 8192;    // NUM_SMALL
constexpr float kEps = 1e-8f;

constexpr int kNSC = kN * kS * kC;                 // combine domain (155,648)
constexpr int kCombineBlocks = 304;                // 304 * 512 == kNSC exactly

// ---- workspace layout (bytes) ----
// Zeroed region first (amax, sumpool, counts, needmask), then fully-
// overwritten buffers (tmask, partials).
constexpr size_t OFF_AMAX = 0;                                   // u64[N*S*C] (value_bits<<32)|~pix
constexpr size_t SZ_AMAX  = (size_t)kN * kS * kC * 8;
constexpr size_t OFF_SUM  = OFF_AMAX + SZ_AMAX;                  // f32[N*Ssm*C] nll sumpool
constexpr size_t SZ_SUM   = (size_t)kN * kSsm * kC * 4;
constexpr size_t OFF_CNT  = OFF_SUM + SZ_SUM;                    // i32[N*Ssm]
constexpr size_t SZ_CNT   = (size_t)kN * kSsm * 4;
constexpr size_t OFF_NM   = OFF_CNT + SZ_CNT;                    // u32[N*Ssm] needed (small,ch) bits
constexpr size_t SZ_NM    = (size_t)kN * kSsm * 4;
constexpr size_t ZERO_BYTES = OFF_NM + SZ_NM;                    // everything above is zeroed
constexpr size_t ZERO_CHUNKS = ZERO_BYTES / 16;                  // 16B chunks (sizes are multiples)
constexpr size_t OFF_TM   = ZERO_BYTES;                          // u32[N*S] target channel bitmask
constexpr size_t SZ_TM    = (size_t)kN * kS * 4;
constexpr size_t OFF_PL   = OFF_TM + SZ_TM;                      // f32[kCombineBlocks]
constexpr size_t SZ_PL    = (size_t)kCombineBlocks * 4;
constexpr size_t OFF_PN   = OFF_PL + SZ_PL;                      // i32[kCombineBlocks]
constexpr size_t SZ_PN    = (size_t)kCombineBlocks * 4;
constexpr size_t WS_TOTAL = OFF_PN + SZ_PN;

// Fused: zero the accumulator region + build tmask.
__global__ void init_kernel(const float* __restrict__ targets,
                            unsigned* __restrict__ tmask,
                            ulong2* __restrict__ ws) {
    size_t gid = (size_t)blockIdx.x * blockDim.x + threadIdx.x;
    if (gid < ZERO_CHUNKS) ws[gid] = ulong2{0ULL, 0ULL};
    if (gid < (size_t)kN * kS) {
        const float* t = targets + gid * (kC + 1);
        unsigned m = 0;
#pragma unroll
        for (int c = 0; c < kC; ++c)
            if (t[c] > 0.f) m |= (1u << c);
        tmask[gid] = m;
    }
}

// Weak branch (1 pixel/thread — R4's 2-pixel variant regressed: 2x VGPR +
// dead-pixel softmax inside live pairs): softmax over C, per-(segment,
// channel) lexicographic argmax via u64 atomicMax of
// (float_bits(v)<<32)|~pixel, only for target channels.
__global__ void weak_argmax_kernel(const float* __restrict__ logits,
                                   const unsigned char* __restrict__ mask,
                                   const int* __restrict__ seg,
                                   const unsigned* __restrict__ tmask,
                                   unsigned long long* __restrict__ amax) {
    int gid = blockIdx.x * blockDim.x + threadIdx.x;
    if (gid >= kN * kHW) return;
    if (!mask[gid]) return;
    int n = gid / kHW;
    int p = gid - n * kHW;
    int s = seg[gid];
    unsigned tm = tmask[n * kS + s];
    if (!tm) return;

    const float* base = logits + (size_t)n * kC * kHW + p;
    float x[kC];
    float m = -1e30f;
#pragma unroll
    for (int c = 0; c < kC; ++c) {
        x[c] = base[(size_t)c * kHW];
        m = fmaxf(m, x[c]);
    }
    float sum = 0.f;
#pragma unroll
    for (int c = 0; c < kC; ++c) {
        x[c] = expf(x[c] - m);
        sum += x[c];
    }
    float inv = 1.f / sum;

    unsigned long long lowbits = (unsigned int)(~(unsigned int)p);
    unsigned long long* dst = amax + ((size_t)n * kS + s) * kC;
#pragma unroll
    for (int c = 0; c < kC; ++c) {
        if (tm & (1u << c)) {
            float v = x[c] * inv;
            unsigned long long key =
                ((unsigned long long)__float_as_uint(v) << 32) | lowbits;
            atomicMax(&dst[c], key);
        }
    }
}

// Mark which (small, channel) pairs the combine stage will read.
__global__ void need_mark_kernel(const unsigned long long* __restrict__ amax,
                                 const unsigned* __restrict__ tmask,
                                 const int* __restrict__ small_w,
                                 unsigned* __restrict__ needmask) {
    int gid = blockIdx.x * blockDim.x + threadIdx.x;
    if (gid >= kNSC) return;
    int n = gid / (kS * kC);
    int rem = gid - n * (kS * kC);
    int s = rem / kC;
    int c = rem - s * kC;
    if (!((tmask[n * kS + s] >> c) & 1u)) return;
    unsigned long long packed = amax[gid];
    if (packed == 0ULL) return;  // empty segment
    unsigned pix = ~(unsigned)(packed & 0xFFFFFFFFULL);
    int sel = small_w[(size_t)n * kHW + pix];
    atomicOr(&needmask[n * kSsm + sel], 1u << c);
}

// Strong branch (1 pixel/thread): only pixels whose small-superpixel is
// needed; only needed channels get the nll atomicAdd.
__global__ void strong_sumpool_kernel(const float* __restrict__ logits,
                                      const unsigned char* __restrict__ mask,
                                      const int* __restrict__ seg,
                                      const unsigned* __restrict__ needmask,
                                      float* __restrict__ sumpool,
                                      int* __restrict__ counts) {
    int gid = blockIdx.x * blockDim.x + threadIdx.x;
    if (gid >= kN * kHW) return;
    if (!mask[gid]) return;
    int n = gid / kHW;
    int p = gid - n * kHW;
    int ss = seg[gid];
    unsigned nm = needmask[n * kSsm + ss];
    if (!nm) return;

    const float* base = logits + (size_t)n * kC * kHW + p;
    float x[kC];
    float m = -1e30f;
#pragma unroll
    for (int c = 0; c < kC; ++c) {
        x[c] = base[(size_t)c * kHW];
        m = fmaxf(m, x[c]);
    }
    float sum = 0.f;
#pragma unroll
    for (int c = 0; c < kC; ++c) {
        x[c] = expf(x[c] - m);
        sum += x[c];
    }
    float inv = 1.f / sum;

    float* dst = sumpool + ((size_t)n * kSsm + ss) * kC;
#pragma unroll
    for (int c = 0; c < kC; ++c) {
        if (nm & (1u << c)) {
            float nll = -logf(x[c] * inv + kEps);
            atomicAdd(&dst[c], nll);
        }
    }
    atomicAdd(&counts[n * kSsm + ss], 1);
}

// Combine: exactly one thread per (n,s,c) — 304 blocks x 512 threads.
// Per-block partials only (R1: same-address atomics serialize at ~13 ns;
// R4: grid-stride + ticket regressed — full parallelism, no ticket).
__global__ void combine_kernel(const unsigned long long* __restrict__ amax,
                               const unsigned* __restrict__ tmask,
                               const int* __restrict__ small_w,
                               const float* __restrict__ sumpool,
                               const int* __restrict__ counts,
                               float* __restrict__ ploss,
                               int* __restrict__ pnv) {
    __shared__ float sLoss[8];
    __shared__ int sNv[8];
    int gid = blockIdx.x * blockDim.x + threadIdx.x;  // < kNSC by construction
    float lv = 0.f;
    int nvv = 0;
    {
        int n = gid / (kS * kC);
        int rem = gid - n * (kS * kC);
        int s = rem / kC;
        int c = rem - s * kC;
        if ((tmask[n * kS + s] >> c) & 1u) {
            unsigned long long packed = amax[gid];
            if (packed != 0ULL) {
                unsigned pix = ~(unsigned)(packed & 0xFFFFFFFFULL);
                int sel = small_w[(size_t)n * kHW + pix];
                lv = sumpool[((size_t)n * kSsm + sel) * kC + c];
                nvv = counts[n * kSsm + sel];
            }
        }
    }
#pragma unroll
    for (int off = 32; off > 0; off >>= 1) {
        lv += __shfl_down(lv, off);
        nvv += __shfl_down(nvv, off);
    }
    int wave = threadIdx.x >> 6;
    if ((threadIdx.x & 63) == 0) {
        sLoss[wave] = lv;
        sNv[wave] = nvv;
    }
    __syncthreads();
    if (threadIdx.x == 0) {
        float tl = 0.f;
        int tn = 0;
#pragma unroll
        for (int w = 0; w < 8; ++w) {
            tl += sLoss[w];
            tn += sNv[w];
        }
        ploss[blockIdx.x] = tl;
        pnv[blockIdx.x] = tn;
    }
}

// Single-block reduction of the per-block partials + final divide.
__global__ void finalize_kernel(const float* __restrict__ ploss,
                                const int* __restrict__ pnv,
                                float* __restrict__ out) {
    __shared__ float sLoss[4];
    __shared__ int sNv[4];
    float lv = 0.f;
    int nvv = 0;
    for (int i = threadIdx.x; i < kCombineBlocks; i += 256) {
        lv += ploss[i];
        nvv += pnv[i];
    }
#pragma unroll
    for (int off = 32; off > 0; off >>= 1) {
        lv += __shfl_down(lv, off);
        nvv += __shfl_down(nvv, off);
    }
    int wave = threadIdx.x >> 6;
    if ((threadIdx.x & 63) == 0) {
        sLoss[wave] = lv;
        sNv[wave] = nvv;
    }
    __syncthreads();
    if (threadIdx.x == 0) {
        float tl = sLoss[0] + sLoss[1] + sLoss[2] + sLoss[3];
        int tn = sNv[0] + sNv[1] + sNv[2] + sNv[3];
        out[0] = tl / (float)(1 + tn);
    }
}

extern "C" void kernel_launch(void* const* d_in, const int* in_sizes, int n_in,
                              void* d_out, int out_size, void* d_ws, size_t ws_size,
                              hipStream_t stream) {
    const float* inputs            = (const float*)d_in[0];
    const float* inputs_weak       = (const float*)d_in[1];
    const float* targets           = (const float*)d_in[2];
    const unsigned char* spmasks      = (const unsigned char*)d_in[3];
    const unsigned char* spmasks_weak = (const unsigned char*)d_in[4];
    // d_in[5] superpixels: unused by the reference
    const int* superpixels_weak    = (const int*)d_in[6];
    const int* superpixel_smalls   = (const int*)d_in[7];
    const int* spx_smalls_weak     = (const int*)d_in[8];
    float* out = (float*)d_out;

    unsigned long long* amax = (unsigned long long*)((char*)d_ws + OFF_AMAX);
    float* sumpool           = (float*)((char*)d_ws + OFF_SUM);
    int* counts              = (int*)((char*)d_ws + OFF_CNT);
    unsigned* needmask       = (unsigned*)((char*)d_ws + OFF_NM);
    unsigned* tmask          = (unsigned*)((char*)d_ws + OFF_TM);
    float* ploss             = (float*)((char*)d_ws + OFF_PL);
    int* pnv                 = (int*)((char*)d_ws + OFF_PN);

    int initThreads = (int)ZERO_CHUNKS;  // 249,856 > kN*kS
    init_kernel<<<(initThreads + 255) / 256, 256, 0, stream>>>(targets, tmask,
                                                               (ulong2*)d_ws);
    int pixTotal = kN * kHW;
    int pixBlocks = (pixTotal + 255) / 256;
    weak_argmax_kernel<<<pixBlocks, 256, 0, stream>>>(inputs_weak, spmasks_weak,
                                                      superpixels_weak, tmask, amax);
    need_mark_kernel<<<(kNSC + 255) / 256, 256, 0, stream>>>(amax, tmask,
                                                             spx_smalls_weak, needmask);
    strong_sumpool_kernel<<<pixBlocks, 256, 0, stream>>>(inputs, spmasks,
                                                         superpixel_smalls,
                                                         needmask, sumpool, counts);
    combine_kernel<<<kCombineBlocks, 512, 0, stream>>>(amax, tmask, spx_smalls_weak,
                                                       sumpool, counts, ploss, pnv);
    finalize_kernel<<<1, 256, 0, stream>>>(ploss, pnv, out);
}